// Round 5
// baseline (135.478 us; speedup 1.0000x reference)
//
#include <hip/hip_runtime.h>
#include <stdint.h>

// N=4096 rows, D=1024 -> M = [Q|K] : 4096 x 2048, Mt = M^T : 2048 x 4096 bf16
// loss = [ sum_{a,b} s_a s_b (M^T M)_ab^2 ] / (N*(N-1)),  s_a = +1 (a<1024), -1 else
// R5: gram is staging-BW-bound (~7.5 TB/s L2/L3, invariant across R1/R3/R4).
//     256x256 tiles halve staged bytes: 268 MB -> 147 MB. 512-thr blocks.
#define N_ROWS 4096
#define DIMS   1024
#define BM 256         // gram tile (square)
#define BK 64
#define TG 8           // 2048/256 tile grid
#define NTRI 36        // 8*9/2 upper-triangular tiles
#define KSPLIT 8
#define KCHUNK 512     // 4096/KSPLIT

typedef __attribute__((ext_vector_type(8))) short short8;
typedef __attribute__((ext_vector_type(8))) unsigned short ushort8;
typedef __attribute__((ext_vector_type(4))) float f32x4;

__device__ __forceinline__ unsigned short f2bf(float f) {
  union { float f; unsigned int u; } c; c.f = f;
  unsigned int u = c.u;
  return (unsigned short)((u + 0x7fffu + ((u >> 16) & 1u)) >> 16);
}
__device__ __forceinline__ float bf2f(unsigned short v) {
  union { float f; unsigned int u; } c; c.u = ((unsigned int)v) << 16;
  return c.f;
}

// async global->LDS, 16B/lane; LDS dest = wave-uniform base + lane*16
__device__ __forceinline__ void async_cp16(const unsigned short* g, void* lds) {
  __builtin_amdgcn_global_load_lds(
      (const __attribute__((address_space(1))) void*)g,
      (__attribute__((address_space(3))) void*)lds, 16, 0, 0);
}

// ---------------------------------------------------------------------------
// K1: inverse row norms of feat_q / feat_k (one wave per row); zero d_out.
// ---------------------------------------------------------------------------
__global__ __launch_bounds__(256) void rownorm_kernel(
    const float* __restrict__ fq, const float* __restrict__ fk,
    float* __restrict__ invq, float* __restrict__ invk, float* __restrict__ out) {
  if (blockIdx.x == 0 && blockIdx.y == 0 && threadIdx.x == 0) out[0] = 0.0f;
  const int w = threadIdx.x >> 6, lane = threadIdx.x & 63;
  const int row = blockIdx.x * 4 + w;
  const float* src = blockIdx.y ? fk : fq;
  float* dst = blockIdx.y ? invk : invq;
  const float4* s4 = (const float4*)(src + (size_t)row * DIMS);
  float ss = 0.0f;
  #pragma unroll
  for (int s = 0; s < 4; ++s) {
    float4 v = s4[lane + 64 * s];
    ss += v.x * v.x + v.y * v.y + v.z * v.z + v.w * v.w;
  }
  #pragma unroll
  for (int off = 32; off > 0; off >>= 1) ss += __shfl_xor(ss, off);
  if (lane == 0) dst[row] = 1.0f / sqrtf(ss);  // eps terms cancel to ~3e-9 rel
}

// ---------------------------------------------------------------------------
// K2: build Mt[a][i] = normalized bf16, transposed via LDS (unchanged).
// ---------------------------------------------------------------------------
__global__ __launch_bounds__(256) void transpose_scale_kernel(
    const float* __restrict__ fq, const float* __restrict__ fk,
    const float* __restrict__ invq, const float* __restrict__ invk,
    unsigned short* __restrict__ Mt) {
  __shared__ unsigned short tile[64][260];
  const int i0 = blockIdx.x * 256;
  const int a0 = blockIdx.y * 64;
  const int w = threadIdx.x >> 6, lane = threadIdx.x & 63;
  const float* src;
  const float* inv;
  int acol;
  if (a0 < DIMS) { src = fq; inv = invq; acol = a0 + lane; }
  else           { src = fk; inv = invk; acol = a0 - DIMS + lane; }

  for (int c0 = 0; c0 < 64; c0 += 4) {
    ushort4 v;
    unsigned short* vp = (unsigned short*)&v;
    #pragma unroll
    for (int c = 0; c < 4; ++c) {
      const int i = i0 + w * 64 + c0 + c;
      vp[c] = f2bf(src[(size_t)i * DIMS + acol] * inv[i]);
    }
    *(ushort4*)&tile[lane][w * 64 + c0] = v;
  }
  __syncthreads();
  #pragma unroll
  for (int r = 0; r < 16; ++r) {
    const int al = w * 16 + r;
    ushort4 v = *(const ushort4*)&tile[al][lane * 4];
    *(ushort4*)(Mt + (size_t)(a0 + al) * N_ROWS + i0 + lane * 4) = v;
  }
}

// ---------------------------------------------------------------------------
// K3: partial Gram tiles, 256x256, 512 threads (8 waves). Wave tile 64x128.
// Waves 0-3 stage A panel (256x64), waves 4-7 stage B. Same XOR-chunk swizzle
// as R1-R4 (verified). Raw bf16 partial stored to slab; NO squaring here.
// ---------------------------------------------------------------------------
__global__ __launch_bounds__(512) void gram_partial_kernel(
    const unsigned short* __restrict__ Mt, unsigned short* __restrict__ Gp) {
  __shared__ __align__(16) char smem[2 * BM * BK * 2];  // 64 KiB: A + B panels

  const int t = blockIdx.x >> 3;
  const int kc = blockIdx.x & 7;
  int I = 0, rem = t;
  while (rem >= (TG - I)) { rem -= (TG - I); ++I; }
  const int J = I + rem;

  const int tid = threadIdx.x, w = tid >> 6, lane = tid & 63;

  // staging: waves 0-3 -> A (rows of panel I); waves 4-7 -> B (panel J)
  const int isB = w >> 2;
  const int rblk = isB ? J : I;
  const int wq = w & 3;                    // quarter of the 256-row panel
  const int rl = lane >> 3;
  const int cl = (lane & 7) ^ rl;          // chunk swizzle (verified R1/R3/R4)
  const bool skipStage = (isB && I == J);  // diag tile: B aliases A
  const unsigned short* gsrc0 =
      Mt + (size_t)(rblk * BM + wq * 64 + rl) * N_ROWS + kc * KCHUNK + cl * 8;
  char* ldsBase = smem + isB * 32768 + wq * 8192;
  const int bOff = (I == J) ? 0 : 32768;

  // compute: wave (wr,wc) owns 64x128 of the 256x256 tile
  const int wr = w >> 1, wc = w & 1;
  const int ml = lane & 15, quad = lane >> 4;
  const int ar0 = wr * 64, bc0 = wc * 128;

  f32x4 acc[4][8] = {};

  for (int kk = 0; kk < KCHUNK; kk += BK) {
    if (!skipStage) {
      const unsigned short* g = gsrc0 + kk;
      #pragma unroll
      for (int s = 0; s < 8; ++s)
        async_cp16(g + (size_t)s * 8 * N_ROWS, ldsBase + s * 1024);
    }
    __syncthreads();
    #pragma unroll
    for (int ks = 0; ks < BK; ks += 32) {
      const int slot = (((ks >> 3) | quad) ^ (ml & 7)) * 16;
      short8 a[4], b[8];
      #pragma unroll
      for (int i = 0; i < 4; ++i) {
        const int ra = (ar0 + i * 16 + ml) * (BK * 2);
        a[i] = *(const short8*)(smem + ra + slot);
      }
      #pragma unroll
      for (int j = 0; j < 8; ++j) {
        const int rb = (bc0 + j * 16 + ml) * (BK * 2);
        b[j] = *(const short8*)(smem + bOff + rb + slot);
      }
      #pragma unroll
      for (int i = 0; i < 4; ++i)
        #pragma unroll
        for (int j = 0; j < 8; ++j)
          acc[i][j] = __builtin_amdgcn_mfma_f32_16x16x32_bf16(a[i], b[j], acc[i][j], 0, 0, 0);
    }
    __syncthreads();
  }

  // epilogue: store raw bf16 partial tile. C/D: col=lane&15, row=quad*4+reg
  unsigned short* slab = Gp + (size_t)blockIdx.x * (BM * BM);
  #pragma unroll
  for (int i = 0; i < 4; ++i)
    #pragma unroll
    for (int j = 0; j < 8; ++j)
      #pragma unroll
      for (int p = 0; p < 4; ++p) {
        const int r = ar0 + i * 16 + quad * 4 + p;
        const int c = bc0 + j * 16 + ml;
        slab[r * BM + c] = f2bf(acc[i][j][p]);
      }
}

// ---------------------------------------------------------------------------
// K4: sum KSPLIT partials (fp32), square, sign/weight, reduce -> atomicAdd.
// Grid: NTRI*32 blocks; block handles 2048 entries of one tile (8/thread).
// ---------------------------------------------------------------------------
__global__ __launch_bounds__(256) void square_reduce_kernel(
    const unsigned short* __restrict__ Gp, float* __restrict__ out) {
  __shared__ float wsum[4];
  const int t = blockIdx.x >> 5;
  const int seg = blockIdx.x & 31;
  int I = 0, rem = t;
  while (rem >= (TG - I)) { rem -= (TG - I); ++I; }
  const int J = I + rem;

  const unsigned short* base =
      Gp + (size_t)t * (KSPLIT * BM * BM) + seg * 2048 + threadIdx.x * 8;
  float s[8] = {0, 0, 0, 0, 0, 0, 0, 0};
  #pragma unroll
  for (int kc = 0; kc < KSPLIT; ++kc) {
    const ushort8 v = *(const ushort8*)(base + kc * (BM * BM));
    #pragma unroll
    for (int x = 0; x < 8; ++x) s[x] += bf2f(v[x]);
  }
  float local = 0.0f;
  #pragma unroll
  for (int x = 0; x < 8; ++x) local += s[x] * s[x];

  const float sgn = ((I < 4) == (J < 4)) ? 1.0f : -1.0f;  // q-panels: I,J < 4
  local *= (I == J ? 1.0f : 2.0f) * sgn;

  #pragma unroll
  for (int off = 32; off > 0; off >>= 1) local += __shfl_xor(local, off);
  const int w = threadIdx.x >> 6, lane = threadIdx.x & 63;
  if (lane == 0) wsum[w] = local;
  __syncthreads();
  if (threadIdx.x == 0) {
    const float ts = wsum[0] + wsum[1] + wsum[2] + wsum[3];
    atomicAdd(out, ts * (1.0f / 16773120.0f));  // / (N*(N-1))
  }
}

extern "C" void kernel_launch(void* const* d_in, const int* in_sizes, int n_in,
                              void* d_out, int out_size, void* d_ws, size_t ws_size,
                              hipStream_t stream) {
  const float* fq = (const float*)d_in[0];
  const float* fk = (const float*)d_in[1];
  float* invq = (float*)d_ws;                                    // 16 KiB
  float* invk = invq + N_ROWS;                                   // 16 KiB
  unsigned short* Mt = (unsigned short*)((char*)d_ws + 32768);   // 16 MiB
  unsigned short* Gp = Mt + (size_t)2048 * N_ROWS;               // 37.7 MiB
  float* out = (float*)d_out;

  rownorm_kernel<<<dim3(N_ROWS / 4, 2), 256, 0, stream>>>(fq, fk, invq, invk, out);
  transpose_scale_kernel<<<dim3(16, 32), 256, 0, stream>>>(fq, fk, invq, invk, Mt);
  gram_partial_kernel<<<NTRI * KSPLIT, 512, 0, stream>>>(Mt, Gp);
  square_reduce_kernel<<<NTRI * 32, 256, 0, stream>>>(Gp, out);
}

// Round 6
// 116.485 us; speedup vs baseline: 1.1631x; 1.1631x over previous
//
#include <hip/hip_runtime.h>
#include <stdint.h>

// N=4096, D=1024 -> M = [Q|K] : 4096 x 2048, Mt = M^T (fp8 e4m3, K-permuted)
// loss = [ sum_{a,b} s_a s_b (M^T M)_ab^2 ] / (N*(N-1)), s_a=+1 (a<1024), -1 else
// R6: staging is the bottleneck (R3==R4 at equal bytes, occupancy x2 -> no change).
//     fp8 Mt halves staged bytes (278->133 MB) keeping R3's exact proven geometry:
//     128x128 tiles, BK=128 (=128B LDS rows, same swizzle), 544 blocks, 32KiB LDS.
//     K-permuted storage: byte pos in 128-block = q*32+s1*16+s0*8+j for
//     k = s1*64+s0*32+q*8+j  => one ds_read_b128 = two 8B fp8 MFMA fragments.
#define N_ROWS 4096
#define DIMS   1024
#define BM 128
#define BK 128         // fp8 elements per LDS row = 128 bytes
#define TG 16
#define NTRI 136
#define KSPLIT 4
#define KCHUNK 1024    // 4096/KSPLIT (fp8 bytes)

typedef __attribute__((ext_vector_type(2))) long longx2;
typedef __attribute__((ext_vector_type(4))) float f32x4;

__device__ __forceinline__ unsigned short f2bf(float f) {
  union { float f; unsigned int u; } c; c.f = f;
  unsigned int u = c.u;
  return (unsigned short)((u + 0x7fffu + ((u >> 16) & 1u)) >> 16);
}
__device__ __forceinline__ float bf2f(unsigned short v) {
  union { float f; unsigned int u; } c; c.u = ((unsigned int)v) << 16;
  return c.f;
}
// pack 4 floats -> 4 fp8 e4m3 bytes (hardware cvt, OCP on gfx950)
__device__ __forceinline__ unsigned int pk4_fp8(float a, float b, float c, float d) {
  int v = __builtin_amdgcn_cvt_pk_fp8_f32(a, b, 0, false);
  v = __builtin_amdgcn_cvt_pk_fp8_f32(c, d, v, true);
  return (unsigned int)v;
}
// async global->LDS, 16B/lane
__device__ __forceinline__ void async_cp16(const unsigned char* g, void* lds) {
  __builtin_amdgcn_global_load_lds(
      (const __attribute__((address_space(1))) void*)g,
      (__attribute__((address_space(3))) void*)lds, 16, 0, 0);
}

// ---------------------------------------------------------------------------
// K1: inverse row norms; zero d_out.
// ---------------------------------------------------------------------------
__global__ __launch_bounds__(256) void rownorm_kernel(
    const float* __restrict__ fq, const float* __restrict__ fk,
    float* __restrict__ invq, float* __restrict__ invk, float* __restrict__ out) {
  if (blockIdx.x == 0 && blockIdx.y == 0 && threadIdx.x == 0) out[0] = 0.0f;
  const int w = threadIdx.x >> 6, lane = threadIdx.x & 63;
  const int row = blockIdx.x * 4 + w;
  const float* src = blockIdx.y ? fk : fq;
  float* dst = blockIdx.y ? invk : invq;
  const float4* s4 = (const float4*)(src + (size_t)row * DIMS);
  float ss = 0.0f;
  #pragma unroll
  for (int s = 0; s < 4; ++s) {
    float4 v = s4[lane + 64 * s];
    ss += v.x * v.x + v.y * v.y + v.z * v.z + v.w * v.w;
  }
  #pragma unroll
  for (int off = 32; off > 0; off >>= 1) ss += __shfl_xor(ss, off);
  if (lane == 0) dst[row] = 1.0f / sqrtf(ss);  // eps terms cancel (~3e-9 rel)
}

// ---------------------------------------------------------------------------
// K2: Mt[a][perm(i)] = fp8(normalized), transposed via LDS (bf16 intermediate;
// double-rounding negligible vs fp8 ulp).
// ---------------------------------------------------------------------------
__global__ __launch_bounds__(256) void transpose_scale_kernel(
    const float* __restrict__ fq, const float* __restrict__ fk,
    const float* __restrict__ invq, const float* __restrict__ invk,
    unsigned char* __restrict__ Mt) {
  __shared__ unsigned short tile[64][260];
  const int i0 = blockIdx.x * 256;
  const int a0 = blockIdx.y * 64;
  const int w = threadIdx.x >> 6, lane = threadIdx.x & 63;
  const float* src;
  const float* inv;
  int acol;
  if (a0 < DIMS) { src = fq; inv = invq; acol = a0 + lane; }
  else           { src = fk; inv = invk; acol = a0 - DIMS + lane; }

  for (int c0 = 0; c0 < 64; c0 += 4) {
    ushort4 v;
    unsigned short* vp = (unsigned short*)&v;
    #pragma unroll
    for (int c = 0; c < 4; ++c) {
      const int i = i0 + w * 64 + c0 + c;
      vp[c] = f2bf(src[(size_t)i * DIMS + acol] * inv[i]);
    }
    *(ushort4*)&tile[lane][w * 64 + c0] = v;
  }
  __syncthreads();
  // write phase: lane covers i = i0 + lane*4 .. +3 (same q,s0,s1; j consecutive)
  const int il = (lane * 4) & 127;
  const int blk = (i0 + lane * 4) >> 7;
  const int q = (il >> 3) & 3, s0 = (il >> 5) & 1, s1 = (il >> 6) & 1;
  const int pos = q * 32 + s1 * 16 + s0 * 8 + (il & 7);
  #pragma unroll
  for (int r = 0; r < 16; ++r) {
    const int al = w * 16 + r;
    ushort4 v = *(const ushort4*)&tile[al][lane * 4];
    const unsigned int p8 = pk4_fp8(bf2f(v.x), bf2f(v.y), bf2f(v.z), bf2f(v.w));
    *(unsigned int*)(Mt + (size_t)(a0 + al) * N_ROWS + blk * 128 + pos) = p8;
  }
}

// ---------------------------------------------------------------------------
// K3: partial Gram tiles, fp8 MFMA. R3 geometry: 128x128 tile, 256 thr, 32KiB
// LDS, 544 blocks. BK=128 => 8 kk iters. Coalesced lane-major slab epilogue.
// ---------------------------------------------------------------------------
__global__ __launch_bounds__(256, 2) void gram_partial_kernel(
    const unsigned char* __restrict__ Mt, unsigned short* __restrict__ Gp) {
  __shared__ __align__(16) char smem[2 * BM * BK];  // 32 KiB: A + B panels

  const int t = blockIdx.x >> 2;
  const int kc = blockIdx.x & 3;
  int I = 0, rem = t;
  while (rem >= (TG - I)) { rem -= (TG - I); ++I; }
  const int J = I + rem;

  const int tid = threadIdx.x, w = tid >> 6, lane = tid & 63;

  // staging: waves 0,1 -> A (rows of block I); waves 2,3 -> B (rows of J)
  const int isB = w >> 1;
  const int rblk = isB ? J : I;
  const int rl = lane >> 3;
  const int cl = (lane & 7) ^ rl;          // chunk swizzle (verified R1/R3/R4)
  const bool skipStage = (isB && I == J);
  const unsigned char* gsrc0 =
      Mt + (size_t)(rblk * BM + (w & 1) * 64 + rl) * N_ROWS + kc * KCHUNK + cl * 16;
  char* ldsBase = smem + isB * 16384 + (w & 1) * 8192;
  const int bOff = (I == J) ? 0 : 16384;

  const int wr = w >> 1, wc = w & 1;
  const int ml = lane & 15, quad = lane >> 4;
  const int ar0 = wr * 64, bc0 = wc * 64;

  f32x4 acc[4][4] = {};

  for (int kk = 0; kk < KCHUNK; kk += BK) {
    if (!skipStage) {
      const unsigned char* g = gsrc0 + kk;
      #pragma unroll
      for (int s = 0; s < 8; ++s)
        async_cp16(g + (size_t)s * 8 * N_ROWS, ldsBase + s * 1024);
    }
    __syncthreads();
    // fragments: chunk c = q*2+s1 holds [frag(ks=s1*64), frag(ks=s1*64+32)]
    longx2 a[4][2], b[4][2];
    #pragma unroll
    for (int i = 0; i < 4; ++i) {
      const int ra = (ar0 + i * 16 + ml) * BK;
      const int rb = (bc0 + i * 16 + ml) * BK;
      #pragma unroll
      for (int s1 = 0; s1 < 2; ++s1) {
        const int slot = ((quad * 2 + s1) ^ (ml & 7)) * 16;
        a[i][s1] = *(const longx2*)(smem + ra + slot);
        b[i][s1] = *(const longx2*)(smem + bOff + rb + slot);
      }
    }
    #pragma unroll
    for (int s1 = 0; s1 < 2; ++s1)
      #pragma unroll
      for (int h = 0; h < 2; ++h)
        #pragma unroll
        for (int i = 0; i < 4; ++i)
          #pragma unroll
          for (int j = 0; j < 4; ++j)
            acc[i][j] = __builtin_amdgcn_mfma_f32_16x16x32_fp8_fp8(
                a[i][s1][h], b[j][s1][h], acc[i][j], 0, 0, 0);
    __syncthreads();
  }

  // epilogue: lane-major coalesced bf16 slab (layout consistent across kc)
  unsigned short* slab = Gp + (size_t)blockIdx.x * (BM * BM) + w * 4096;
  #pragma unroll
  for (int i = 0; i < 4; ++i)
    #pragma unroll
    for (int j = 0; j < 4; ++j) {
      ushort4 o;
      o.x = f2bf(acc[i][j][0]); o.y = f2bf(acc[i][j][1]);
      o.z = f2bf(acc[i][j][2]); o.w = f2bf(acc[i][j][3]);
      *(ushort4*)(slab + (i * 4 + j) * 256 + lane * 4) = o;
    }
}

// ---------------------------------------------------------------------------
// K4: sum KSPLIT partials (fp32), square, sign/weight, reduce -> atomicAdd.
// ---------------------------------------------------------------------------
__global__ __launch_bounds__(256) void square_reduce_kernel(
    const unsigned short* __restrict__ Gp, float* __restrict__ out) {
  __shared__ float wsum[4];
  const int t = blockIdx.x >> 3;
  const int seg = blockIdx.x & 7;
  int I = 0, rem = t;
  while (rem >= (TG - I)) { rem -= (TG - I); ++I; }
  const int J = I + rem;

  const unsigned short* base =
      Gp + (size_t)t * (KSPLIT * BM * BM) + seg * 2048 + threadIdx.x * 8;
  float s[8] = {0, 0, 0, 0, 0, 0, 0, 0};
  #pragma unroll
  for (int kc = 0; kc < KSPLIT; ++kc) {
    const ushort4 v0 = *(const ushort4*)(base + kc * (BM * BM));
    const ushort4 v1 = *(const ushort4*)(base + kc * (BM * BM) + 4);
    s[0] += bf2f(v0.x); s[1] += bf2f(v0.y); s[2] += bf2f(v0.z); s[3] += bf2f(v0.w);
    s[4] += bf2f(v1.x); s[5] += bf2f(v1.y); s[6] += bf2f(v1.z); s[7] += bf2f(v1.w);
  }
  float local = 0.0f;
  #pragma unroll
  for (int x = 0; x < 8; ++x) local += s[x] * s[x];

  const float sgn = ((I < 8) == (J < 8)) ? 1.0f : -1.0f;
  local *= (I == J ? 1.0f : 2.0f) * sgn;

  #pragma unroll
  for (int off = 32; off > 0; off >>= 1) local += __shfl_xor(local, off);
  const int w = threadIdx.x >> 6, lane = threadIdx.x & 63;
  if (lane == 0) wsum[w] = local;
  __syncthreads();
  if (threadIdx.x == 0) {
    const float ts = wsum[0] + wsum[1] + wsum[2] + wsum[3];
    atomicAdd(out, ts * (1.0f / 16773120.0f));  // / (N*(N-1))
  }
}

extern "C" void kernel_launch(void* const* d_in, const int* in_sizes, int n_in,
                              void* d_out, int out_size, void* d_ws, size_t ws_size,
                              hipStream_t stream) {
  const float* fq = (const float*)d_in[0];
  const float* fk = (const float*)d_in[1];
  float* invq = (float*)d_ws;                                    // 16 KiB
  float* invk = invq + N_ROWS;                                   // 16 KiB
  unsigned char* Mt = (unsigned char*)d_ws + 32768;              // 8 MiB fp8
  unsigned short* Gp = (unsigned short*)(Mt + (size_t)2048 * N_ROWS);  // 17.8 MiB
  float* out = (float*)d_out;

  rownorm_kernel<<<dim3(N_ROWS / 4, 2), 256, 0, stream>>>(fq, fk, invq, invk, out);
  transpose_scale_kernel<<<dim3(16, 32), 256, 0, stream>>>(fq, fk, invq, invk, Mt);
  gram_partial_kernel<<<NTRI * KSPLIT, 256, 0, stream>>>(Mt, Gp);
  square_reduce_kernel<<<NTRI * 8, 256, 0, stream>>>(Gp, out);
}